// Round 8
// baseline (111.105 us; speedup 1.0000x reference)
//
#include <hip/hip_runtime.h>

#define BINS 10
#define ROWW 11   // padded words per thread-private LDS row (11 coprime 32 banks)

// ===== ELEM MATH: byte-for-byte from R2 (the last build that PASSED, absmax 0.0).
// Only the scatter target changed: wave-shared row (contended) -> thread-private
// row (uncontended), still atomicAdd (ds_add_f32, hardware-ordered RMW).
__device__ __forceinline__ void ghm_elem(float x, float tt,
                                         unsigned long long& pk,
                                         float* my) {
    float t = __expf(-fabsf(x));                 // e^{-|x|}
    float u = 1.f + t;
    float r = __builtin_amdgcn_rcpf(u);          // ~1ulp approx, ample slack
    float sig = (x >= 0.f) ? r : t * r;          // sigmoid(x), all ranges
    float d = sig - tt;
    int idx = (int)(fabsf(d) * 10.f);            // trunc
    idx = idx < 9 ? idx : 9;
    pk += 1ull << (6 * idx);                     // packed counts, 6b/bin
    float bce = fmaxf(x, 0.f) - x * tt + __logf(u);  // log1p(e^{-|x|}) = log(u)
    atomicAdd(&my[idx], bce);                    // private row: no contention
}

__global__ __launch_bounds__(256) void ghm_pass1(
    const float* __restrict__ pred, const float* __restrict__ tgt,
    long long n, int nb,
    float* __restrict__ bsum, int* __restrict__ bcnt)
{
    __shared__ float hist[256 * ROWW];   // 11.0 KB: per-thread private rows
    __shared__ float rsum[4][BINS];
    __shared__ int   rcnt[4][BINS];

    const int tid  = threadIdx.x;
    const int lane = tid & 63;
    const int wave = tid >> 6;
    float* my = &hist[tid * ROWW];
#pragma unroll
    for (int b = 0; b < BINS; ++b) my[b] = 0.f;

    unsigned long long pk = 0;
    int c[BINS];
#pragma unroll
    for (int b = 0; b < BINS; ++b) c[b] = 0;

    const long long n4 = n >> 2;
    const float4* p4 = (const float4*)pred;
    const float4* t4 = (const float4*)tgt;
    const long long stride = (long long)nb * 256;

    int chunk = 0;
    for (long long i = (long long)blockIdx.x * 256 + tid; i < n4; i += stride) {
        float4 p = p4[i];
        float4 t = t4[i];
        ghm_elem(p.x, t.x, pk, my);
        ghm_elem(p.y, t.y, pk, my);
        ghm_elem(p.z, t.z, pk, my);
        ghm_elem(p.w, t.w, pk, my);
        if (++chunk == 15) {             // <=60 elems per 6-bit field
            chunk = 0;
#pragma unroll
            for (int b = 0; b < BINS; ++b) c[b] += (int)((pk >> (6 * b)) & 63u);
            pk = 0;
        }
    }
    const long long tail0 = n4 << 2;     // tail: block 0, <=3 elems
    if (blockIdx.x == 0 && (long long)tid < (n - tail0))
        ghm_elem(pred[tail0 + tid], tgt[tail0 + tid], pk, my);
#pragma unroll
    for (int b = 0; b < BINS; ++b) c[b] += (int)((pk >> (6 * b)) & 63u);

    __syncthreads();                     // all LDS atomics drained

    // block reduce: own LDS row -> shuffle tree per bin (deterministic;
    // same shuffle pattern R2 used for counts, applied to v and k jointly)
#pragma unroll
    for (int b = 0; b < BINS; ++b) {
        float v = my[b];
        int   k = c[b];
        for (int off = 32; off; off >>= 1) {
            v += __shfl_down(v, off);
            k += __shfl_down(k, off);
        }
        if (lane == 0) { rsum[wave][b] = v; rcnt[wave][b] = k; }
    }
    __syncthreads();
    if (tid < BINS) {
        int b = tid;
        float v = rsum[0][b] + rsum[1][b] + rsum[2][b] + rsum[3][b];
        int   k = rcnt[0][b] + rcnt[1][b] + rcnt[2][b] + rcnt[3][b];
        bsum[(long long)b * nb + blockIdx.x] = v;   // bin-major partials
        bcnt[(long long)b * nb + blockIdx.x] = k;
    }
}

// 10 waves, one bin per wave: parallel strided loads, shuffle reduce.
// Byte-for-byte from R2 (passed).
__global__ __launch_bounds__(640) void ghm_pass2(
    const float* __restrict__ bsum, const int* __restrict__ bcnt,
    int nb, float* __restrict__ out)
{
    __shared__ double    ssum[BINS];
    __shared__ long long scnt[BINS];
    const int lane = threadIdx.x & 63;
    const int wave = threadIdx.x >> 6;   // 0..9 == bin

    double    acc = 0.0;
    long long cc  = 0;
    for (int i = lane; i < nb; i += 64) {
        acc += (double)bsum[(long long)wave * nb + i];
        cc  += (long long)bcnt[(long long)wave * nb + i];
    }
    for (int off = 32; off; off >>= 1) {
        acc += __shfl_down(acc, off);
        cc  += __shfl_down(cc, off);
    }
    if (lane == 0) { ssum[wave] = acc; scnt[wave] = cc; }
    __syncthreads();

    if (threadIdx.x == 0) {
        int n = 0;
#pragma unroll
        for (int b = 0; b < BINS; ++b) n += (scnt[b] > 0) ? 1 : 0;
        double loss = 0.0;
        if (n > 0) {
#pragma unroll
            for (int b = 0; b < BINS; ++b)
                if (scnt[b] > 0)
                    loss += ssum[b] / ((double)scnt[b] * (double)n);
        }
        out[0] = (float)loss;
    }
}

extern "C" void kernel_launch(void* const* d_in, const int* in_sizes, int n_in,
                              void* d_out, int out_size, void* d_ws, size_t ws_size,
                              hipStream_t stream) {
    const float* pred = (const float*)d_in[0];
    const float* tgt  = (const float*)d_in[1];
    float* out = (float*)d_out;
    const long long n = (long long)in_sizes[0];

    int nb = 2048;
    const size_t per_block = (size_t)BINS * (sizeof(float) + sizeof(int)); // 80 B
    while (nb > 1 && (size_t)nb * per_block > ws_size) nb >>= 1;

    float* bsum = (float*)d_ws;
    int*   bcnt = (int*)((char*)d_ws + (size_t)nb * BINS * sizeof(float));

    ghm_pass1<<<nb, 256, 0, stream>>>(pred, tgt, n, nb, bsum, bcnt);
    ghm_pass2<<<1, 640, 0, stream>>>(bsum, bcnt, nb, out);
}

// Round 9
// 47.523 us; speedup vs baseline: 2.3379x; 2.3379x over previous
//
#include <hip/hip_runtime.h>

#define BINS 10
#define ROWW 11   // padded words per thread-private LDS row (11 coprime 32 banks)

// ===== ELEM MATH: byte-for-byte from R2/R8 (both PASSED absmax 0.0). The
// algebraically-equivalent z-form (R3-R7) fails on HW for reasons not yet
// isolated — do not "simplify" this math without an A/B round.
//
// Scatter: non-atomic RMW on a THREAD-PRIVATE row through a VOLATILE pointer.
// - private row  => single writer, atomicity unnecessary
// - volatile     => compiler cannot reorder/batch the volatile ds_read/ds_write
//                   pairs across elements (R3-R6's lost-update bug); DS ops from
//                   one wave are processed in program order by the LDS pipe.
// - R8's atomicAdd was correct but ~190k cyc/CU: generic-pointer float atomic
//   goes down a per-lane slow path. Plain ds_read+add+ds_write is wave-wide.
__device__ __forceinline__ void ghm_elem(float x, float tt,
                                         unsigned long long& pk,
                                         volatile float* my) {
    float t = __expf(-fabsf(x));                 // e^{-|x|}
    float u = 1.f + t;
    float r = __builtin_amdgcn_rcpf(u);          // ~1ulp approx, ample slack
    float sig = (x >= 0.f) ? r : t * r;          // sigmoid(x), all ranges
    float d = sig - tt;
    int idx = (int)(fabsf(d) * 10.f);            // trunc
    idx = idx < 9 ? idx : 9;
    pk += 1ull << (6 * idx);                     // packed counts, 6b/bin
    float bce = fmaxf(x, 0.f) - x * tt + __logf(u);  // log1p(e^{-|x|}) = log(u)
    my[idx] = my[idx] + bce;                     // ordered volatile RMW
}

__global__ __launch_bounds__(256) void ghm_pass1(
    const float* __restrict__ pred, const float* __restrict__ tgt,
    long long n, int nb,
    float* __restrict__ bsum, int* __restrict__ bcnt)
{
    __shared__ float hist[256 * ROWW];   // 11.0 KB: per-thread private rows
    __shared__ float rsum[4][BINS];
    __shared__ int   rcnt[4][BINS];

    const int tid  = threadIdx.x;
    const int lane = tid & 63;
    const int wave = tid >> 6;
    volatile float* my = &hist[tid * ROWW];
#pragma unroll
    for (int b = 0; b < BINS; ++b) my[b] = 0.f;

    unsigned long long pk = 0;
    int c[BINS];
#pragma unroll
    for (int b = 0; b < BINS; ++b) c[b] = 0;

    const long long n4 = n >> 2;
    const float4* p4 = (const float4*)pred;
    const float4* t4 = (const float4*)tgt;
    const long long stride = (long long)nb * 256;

    int chunk = 0;
    for (long long i = (long long)blockIdx.x * 256 + tid; i < n4; i += stride) {
        float4 p = p4[i];
        float4 t = t4[i];
        ghm_elem(p.x, t.x, pk, my);
        ghm_elem(p.y, t.y, pk, my);
        ghm_elem(p.z, t.z, pk, my);
        ghm_elem(p.w, t.w, pk, my);
        if (++chunk == 15) {             // <=60 elems per 6-bit field
            chunk = 0;
#pragma unroll
            for (int b = 0; b < BINS; ++b) c[b] += (int)((pk >> (6 * b)) & 63u);
            pk = 0;
        }
    }
    const long long tail0 = n4 << 2;     // tail: block 0, <=3 elems
    if (blockIdx.x == 0 && (long long)tid < (n - tail0))
        ghm_elem(pred[tail0 + tid], tgt[tail0 + tid], pk, my);
#pragma unroll
    for (int b = 0; b < BINS; ++b) c[b] += (int)((pk >> (6 * b)) & 63u);

    // block reduce: own LDS row (same-thread, program-ordered) -> shuffle tree
#pragma unroll
    for (int b = 0; b < BINS; ++b) {
        float v = my[b];
        int   k = c[b];
        for (int off = 32; off; off >>= 1) {
            v += __shfl_down(v, off);
            k += __shfl_down(k, off);
        }
        if (lane == 0) { rsum[wave][b] = v; rcnt[wave][b] = k; }
    }
    __syncthreads();
    if (tid < BINS) {
        int b = tid;
        float v = rsum[0][b] + rsum[1][b] + rsum[2][b] + rsum[3][b];
        int   k = rcnt[0][b] + rcnt[1][b] + rcnt[2][b] + rcnt[3][b];
        bsum[(long long)b * nb + blockIdx.x] = v;   // bin-major partials
        bcnt[(long long)b * nb + blockIdx.x] = k;
    }
}

// 10 waves, one bin per wave: parallel strided loads, shuffle reduce.
// Byte-for-byte from R2/R8 (passed).
__global__ __launch_bounds__(640) void ghm_pass2(
    const float* __restrict__ bsum, const int* __restrict__ bcnt,
    int nb, float* __restrict__ out)
{
    __shared__ double    ssum[BINS];
    __shared__ long long scnt[BINS];
    const int lane = threadIdx.x & 63;
    const int wave = threadIdx.x >> 6;   // 0..9 == bin

    double    acc = 0.0;
    long long cc  = 0;
    for (int i = lane; i < nb; i += 64) {
        acc += (double)bsum[(long long)wave * nb + i];
        cc  += (long long)bcnt[(long long)wave * nb + i];
    }
    for (int off = 32; off; off >>= 1) {
        acc += __shfl_down(acc, off);
        cc  += __shfl_down(cc, off);
    }
    if (lane == 0) { ssum[wave] = acc; scnt[wave] = cc; }
    __syncthreads();

    if (threadIdx.x == 0) {
        int n = 0;
#pragma unroll
        for (int b = 0; b < BINS; ++b) n += (scnt[b] > 0) ? 1 : 0;
        double loss = 0.0;
        if (n > 0) {
#pragma unroll
            for (int b = 0; b < BINS; ++b)
                if (scnt[b] > 0)
                    loss += ssum[b] / ((double)scnt[b] * (double)n);
        }
        out[0] = (float)loss;
    }
}

extern "C" void kernel_launch(void* const* d_in, const int* in_sizes, int n_in,
                              void* d_out, int out_size, void* d_ws, size_t ws_size,
                              hipStream_t stream) {
    const float* pred = (const float*)d_in[0];
    const float* tgt  = (const float*)d_in[1];
    float* out = (float*)d_out;
    const long long n = (long long)in_sizes[0];

    int nb = 2048;
    const size_t per_block = (size_t)BINS * (sizeof(float) + sizeof(int)); // 80 B
    while (nb > 1 && (size_t)nb * per_block > ws_size) nb >>= 1;

    float* bsum = (float*)d_ws;
    int*   bcnt = (int*)((char*)d_ws + (size_t)nb * BINS * sizeof(float));

    ghm_pass1<<<nb, 256, 0, stream>>>(pred, tgt, n, nb, bsum, bcnt);
    ghm_pass2<<<1, 640, 0, stream>>>(bsum, bcnt, nb, out);
}

// Round 10
// 46.831 us; speedup vs baseline: 2.3725x; 1.0148x over previous
//
#include <hip/hip_runtime.h>

#define BINS 10

// ===== ELEM MATH: byte-for-byte from R2/R8 (both PASSED absmax 0.0). The
// algebraically-equivalent z-form (R3-R7) fails on HW (deterministic ~0.2
// error, unexplained) — do not reintroduce it without an A/B round.
//
// Scatter: REGISTER predicated adds (R1's structure, passed absmax 0.0).
// R9's LDS volatile RMW was ordering/latency-bound (VALUBusy 30%, waves in
// lgkmcnt waits); 10 predicated register adds are pure VALU and pipeline
// freely. Counts stay in the packed u64 (5 slots vs 30 for predicated ints).
__device__ __forceinline__ void ghm_elem(float x, float tt,
                                         unsigned long long& pk,
                                         float (&s)[BINS]) {
    float t = __expf(-fabsf(x));                 // e^{-|x|}
    float u = 1.f + t;
    float r = __builtin_amdgcn_rcpf(u);          // ~1ulp approx, ample slack
    float sig = (x >= 0.f) ? r : t * r;          // sigmoid(x), all ranges
    float d = sig - tt;
    int idx = (int)(fabsf(d) * 10.f);            // trunc (validated in R8)
    idx = idx < 9 ? idx : 9;
    pk += 1ull << (6 * idx);                     // packed counts, 6b/bin
    float bce = fmaxf(x, 0.f) - x * tt + __logf(u);  // log1p(e^{-|x|}) = log(u)
#pragma unroll
    for (int b = 0; b < BINS; ++b)               // 10x cmp+cndmask+add
        s[b] += (idx == b) ? bce : 0.f;
}

__global__ __launch_bounds__(256) void ghm_pass1(
    const float* __restrict__ pred, const float* __restrict__ tgt,
    long long n, int nb,
    float* __restrict__ bsum, int* __restrict__ bcnt)
{
    __shared__ float rsum[4][BINS];
    __shared__ int   rcnt[4][BINS];

    const int tid  = threadIdx.x;
    const int lane = tid & 63;
    const int wave = tid >> 6;

    float s[BINS];
#pragma unroll
    for (int b = 0; b < BINS; ++b) s[b] = 0.f;
    unsigned long long pk = 0;
    int c[BINS];
#pragma unroll
    for (int b = 0; b < BINS; ++b) c[b] = 0;

    const long long n4 = n >> 2;
    const float4* p4 = (const float4*)pred;
    const float4* t4 = (const float4*)tgt;
    const long long stride = (long long)nb * 256;

    int chunk = 0;
    for (long long i = (long long)blockIdx.x * 256 + tid; i < n4; i += stride) {
        float4 p = p4[i];
        float4 t = t4[i];
        ghm_elem(p.x, t.x, pk, s);
        ghm_elem(p.y, t.y, pk, s);
        ghm_elem(p.z, t.z, pk, s);
        ghm_elem(p.w, t.w, pk, s);
        if (++chunk == 15) {             // <=60 elems per 6-bit field
            chunk = 0;
#pragma unroll
            for (int b = 0; b < BINS; ++b) c[b] += (int)((pk >> (6 * b)) & 63u);
            pk = 0;
        }
    }
    const long long tail0 = n4 << 2;     // tail: block 0, <=3 elems
    if (blockIdx.x == 0 && (long long)tid < (n - tail0))
        ghm_elem(pred[tail0 + tid], tgt[tail0 + tid], pk, s);
#pragma unroll
    for (int b = 0; b < BINS; ++b) c[b] += (int)((pk >> (6 * b)) & 63u);

    // block reduce: shuffle tree per bin, then cross-wave via LDS (R1-proven)
#pragma unroll
    for (int b = 0; b < BINS; ++b) {
        float v = s[b];
        int   k = c[b];
        for (int off = 32; off; off >>= 1) {
            v += __shfl_down(v, off);
            k += __shfl_down(k, off);
        }
        if (lane == 0) { rsum[wave][b] = v; rcnt[wave][b] = k; }
    }
    __syncthreads();
    if (tid < BINS) {
        int b = tid;
        float v = rsum[0][b] + rsum[1][b] + rsum[2][b] + rsum[3][b];
        int   k = rcnt[0][b] + rcnt[1][b] + rcnt[2][b] + rcnt[3][b];
        bsum[(long long)b * nb + blockIdx.x] = v;   // bin-major partials
        bcnt[(long long)b * nb + blockIdx.x] = k;
    }
}

// 10 waves, one bin per wave: parallel strided loads, shuffle reduce.
// Byte-for-byte from R2/R8/R9 (passed).
__global__ __launch_bounds__(640) void ghm_pass2(
    const float* __restrict__ bsum, const int* __restrict__ bcnt,
    int nb, float* __restrict__ out)
{
    __shared__ double    ssum[BINS];
    __shared__ long long scnt[BINS];
    const int lane = threadIdx.x & 63;
    const int wave = threadIdx.x >> 6;   // 0..9 == bin

    double    acc = 0.0;
    long long cc  = 0;
    for (int i = lane; i < nb; i += 64) {
        acc += (double)bsum[(long long)wave * nb + i];
        cc  += (long long)bcnt[(long long)wave * nb + i];
    }
    for (int off = 32; off; off >>= 1) {
        acc += __shfl_down(acc, off);
        cc  += __shfl_down(cc, off);
    }
    if (lane == 0) { ssum[wave] = acc; scnt[wave] = cc; }
    __syncthreads();

    if (threadIdx.x == 0) {
        int n = 0;
#pragma unroll
        for (int b = 0; b < BINS; ++b) n += (scnt[b] > 0) ? 1 : 0;
        double loss = 0.0;
        if (n > 0) {
#pragma unroll
            for (int b = 0; b < BINS; ++b)
                if (scnt[b] > 0)
                    loss += ssum[b] / ((double)scnt[b] * (double)n);
        }
        out[0] = (float)loss;
    }
}

extern "C" void kernel_launch(void* const* d_in, const int* in_sizes, int n_in,
                              void* d_out, int out_size, void* d_ws, size_t ws_size,
                              hipStream_t stream) {
    const float* pred = (const float*)d_in[0];
    const float* tgt  = (const float*)d_in[1];
    float* out = (float*)d_out;
    const long long n = (long long)in_sizes[0];

    int nb = 2048;
    const size_t per_block = (size_t)BINS * (sizeof(float) + sizeof(int)); // 80 B
    while (nb > 1 && (size_t)nb * per_block > ws_size) nb >>= 1;

    float* bsum = (float*)d_ws;
    int*   bcnt = (int*)((char*)d_ws + (size_t)nb * BINS * sizeof(float));

    ghm_pass1<<<nb, 256, 0, stream>>>(pred, tgt, n, nb, bsum, bcnt);
    ghm_pass2<<<1, 640, 0, stream>>>(bsum, bcnt, nb, out);
}